// Round 9
// baseline (656.484 us; speedup 1.0000x reference)
//
#include <hip/hip_runtime.h>
#include <cstdint>

constexpr int kHashSize = 1 << 17;
constexpr uint32_t kHashMask = (uint32_t)kHashSize - 1u;
constexpr int kBuckets = 32 * 32 * 32;  // spatial sort grid

typedef float f2 __attribute__((ext_vector_type(2)));
typedef float f4 __attribute__((ext_vector_type(4)));

// Static per-level resolutions: max(1, round(16 * b**l)), b = 16^(1/11)
__constant__ float kRes[12] = {16.f,  21.f,  26.f,  34.f,  44.f,  56.f,
                               73.f,  93.f,  120.f, 155.f, 199.f, 256.f};

// ---------- sort pass 0: zero histogram ----------
__global__ __launch_bounds__(256) void k_zero(uint32_t* hist) {
  int i = blockIdx.x * 256 + threadIdx.x;
  if (i < kBuckets) hist[i] = 0u;
}

__device__ __forceinline__ uint32_t cell_of(float px, float py, float pz) {
  uint32_t ix = (uint32_t)min(31, (int)(px * 32.f));
  uint32_t iy = (uint32_t)min(31, (int)(py * 32.f));
  uint32_t iz = (uint32_t)min(31, (int)(pz * 32.f));
  return (ix << 10) | (iy << 5) | iz;
}

// ---------- sort pass 1: histogram only (no aux buffers) ----------
__global__ __launch_bounds__(256) void k_hist(const float* __restrict__ x,
                                              uint32_t* __restrict__ hist,
                                              int npts) {
  int n = blockIdx.x * 256 + threadIdx.x;
  if (n >= npts) return;
  atomicAdd(&hist[cell_of(x[3 * n], x[3 * n + 1], x[3 * n + 2])], 1u);
}

// ---------- sort pass 2: exclusive scan, 1 block (1024 thr x 32 each) -------
__global__ __launch_bounds__(1024) void k_scan(uint32_t* __restrict__ hist) {
  __shared__ uint32_t lds[1024];
  const int t = threadIdx.x;
  uint32_t v[32];
  uint32_t s = 0;
#pragma unroll
  for (int i = 0; i < 32; ++i) {
    v[i] = hist[t * 32 + i];
    s += v[i];
  }
  lds[t] = s;
  __syncthreads();
  for (int off = 1; off < 1024; off <<= 1) {
    uint32_t add = (t >= off) ? lds[t - off] : 0u;
    __syncthreads();
    lds[t] += add;
    __syncthreads();
  }
  uint32_t run = lds[t] - s;
#pragma unroll
  for (int i = 0; i < 32; ++i) {
    uint32_t c = v[i];
    hist[t * 32 + i] = run;
    run += c;
  }
}

// ---------- sort pass 3: scatter (atomic bump of scanned bases) ----------
__global__ __launch_bounds__(256) void k_scatter(const float* __restrict__ x,
                                                 uint32_t* __restrict__ hist,
                                                 f4* __restrict__ pts, int npts) {
  int n = blockIdx.x * 256 + threadIdx.x;
  if (n >= npts) return;
  f4 p;
  p.x = x[3 * n + 0];
  p.y = x[3 * n + 1];
  p.z = x[3 * n + 2];
  p.w = __uint_as_float((uint32_t)n);
  uint32_t pos = atomicAdd(&hist[cell_of(p.x, p.y, p.z)], 1u);
  pts[pos] = p;
}

// ---------- one level's interpolated feature ----------
__device__ __forceinline__ f2 level_feat(int l, float px, float py, float pz,
                                         const f2* __restrict__ tbl2) {
  const float r = kRes[l];
  const float xs = px * r, ys = py * r, zs = pz * r;
  const float fx = floorf(xs), fy = floorf(ys), fz = floorf(zs);
  const float wx = xs - fx, wy = ys - fy, wz = zs - fz;
  const uint32_t ix = (uint32_t)(int32_t)fx;
  const uint32_t iy = (uint32_t)(int32_t)fy;
  const uint32_t iz = (uint32_t)(int32_t)fz;
  // incremental spatial hash (uint32 wraparound == reference int32 semantics)
  const uint32_t hx0 = ix * 73856093u, hx1 = hx0 + 73856093u;
  const uint32_t hy0 = iy * 19349663u, hy1 = hy0 + 19349663u;
  const uint32_t hz0 = iz * 83492791u, hz1 = hz0 + 83492791u;
  const f2* __restrict__ t = tbl2 + (size_t)l * kHashSize;
  const f2 f000 = t[(hx0 ^ hy0 ^ hz0) & kHashMask];
  const f2 f001 = t[(hx0 ^ hy0 ^ hz1) & kHashMask];
  const f2 f010 = t[(hx0 ^ hy1 ^ hz0) & kHashMask];
  const f2 f011 = t[(hx0 ^ hy1 ^ hz1) & kHashMask];
  const f2 f100 = t[(hx1 ^ hy0 ^ hz0) & kHashMask];
  const f2 f101 = t[(hx1 ^ hy0 ^ hz1) & kHashMask];
  const f2 f110 = t[(hx1 ^ hy1 ^ hz0) & kHashMask];
  const f2 f111 = t[(hx1 ^ hy1 ^ hz1) & kHashMask];
  const float ax0 = 1.f - wx, ax1 = wx;
  const float by0 = 1.f - wy, by1 = wy;
  const float cz0 = 1.f - wz, cz1 = wz;
  const float ab00 = ax0 * by0, ab01 = ax0 * by1;
  const float ab10 = ax1 * by0, ab11 = ax1 * by1;
  const float w000 = ab00 * cz0, w001 = ab00 * cz1;
  const float w010 = ab01 * cz0, w011 = ab01 * cz1;
  const float w100 = ab10 * cz0, w101 = ab10 * cz1;
  const float w110 = ab11 * cz0, w111 = ab11 * cz1;
  f2 a;
  a.x = w000 * f000.x + w001 * f001.x + w010 * f010.x + w011 * f011.x +
        w100 * f100.x + w101 * f101.x + w110 * f110.x + w111 * f111.x;
  a.y = w000 * f000.y + w001 * f001.y + w010 * f010.y + w011 * f011.y +
        w100 * f100.y + w101 * f101.y + w110 * f110.y + w111 * f111.y;
  return a;
}

// ---------- main: sorted points, load-balanced level->XCD-slot map ----------
// slot 0-3: levels {8,9,10}  (~4.85M req/XCD, 3MB tables resident)
// slot 4-6: levels {6,7,11}  (~4.17M req/XCD, 3MB)
// slot 7  : levels {0..5}    (~3.5M req/XCD, coarse, heavy dedup)
__global__ __launch_bounds__(256) void hashenc_part(
    const f4* __restrict__ pts, const float* __restrict__ tables,
    float* __restrict__ out, int npts, int nb) {
  const int b = blockIdx.x;
  const int c = b & 7;  // XCD slot (round-robin, verified R5)
  const int r = b >> 3;
  int grp, sub;
  if (c < 4) {
    grp = 0;
    sub = r * 4 + c;
  } else if (c < 7) {
    grp = 1;
    sub = r * 3 + (c - 4);
  } else {
    grp = 2;
    sub = r;
  }
  if (sub >= nb) return;
  const int n = sub * 256 + (int)threadIdx.x;
  if (n >= npts) return;

  const f4 p = pts[n];
  const float px = p.x, py = p.y, pz = p.z;
  const uint32_t orig = __float_as_uint(p.w);

  const f2* __restrict__ tbl2 = reinterpret_cast<const f2*>(tables);
  f4* __restrict__ o4 = reinterpret_cast<f4*>(out) + (size_t)orig * 6;
  f2* __restrict__ o2 = reinterpret_cast<f2*>(out) + (size_t)orig * 12;

  if (grp == 0) {  // levels 8,9,10 -> f4 @byte64 + f2 @byte80
    f2 a8 = level_feat(8, px, py, pz, tbl2);
    f2 a9 = level_feat(9, px, py, pz, tbl2);
    f2 a10 = level_feat(10, px, py, pz, tbl2);
    f4 v;
    v.x = a8.x; v.y = a8.y; v.z = a9.x; v.w = a9.y;
    __builtin_nontemporal_store(v, o4 + 4);
    __builtin_nontemporal_store(a10, o2 + 10);
  } else if (grp == 1) {  // levels 6,7,11 -> f4 @byte48 + f2 @byte88
    f2 a6 = level_feat(6, px, py, pz, tbl2);
    f2 a7 = level_feat(7, px, py, pz, tbl2);
    f2 a11 = level_feat(11, px, py, pz, tbl2);
    f4 v;
    v.x = a6.x; v.y = a6.y; v.z = a7.x; v.w = a7.y;
    __builtin_nontemporal_store(v, o4 + 3);
    __builtin_nontemporal_store(a11, o2 + 11);
  } else {  // levels 0..5 -> 3x f4 @byte0
    f2 a0 = level_feat(0, px, py, pz, tbl2);
    f2 a1 = level_feat(1, px, py, pz, tbl2);
    f2 a2 = level_feat(2, px, py, pz, tbl2);
    f2 a3 = level_feat(3, px, py, pz, tbl2);
    f2 a4 = level_feat(4, px, py, pz, tbl2);
    f2 a5 = level_feat(5, px, py, pz, tbl2);
    f4 v0, v1, v2;
    v0.x = a0.x; v0.y = a0.y; v0.z = a1.x; v0.w = a1.y;
    v1.x = a2.x; v1.y = a2.y; v1.z = a3.x; v1.w = a3.y;
    v2.x = a4.x; v2.y = a4.y; v2.z = a5.x; v2.w = a5.y;
    __builtin_nontemporal_store(v0, o4 + 0);
    __builtin_nontemporal_store(v1, o4 + 1);
    __builtin_nontemporal_store(v2, o4 + 2);
  }
}

// ---------- fallback (round-5 kernel, 410us) if ws too small ----------
__global__ __launch_bounds__(256) void hashenc_grouped(
    const float* __restrict__ x, const float* __restrict__ tables,
    float* __restrict__ out, int npts, int bpg) {
  const int b = blockIdx.x;
  const int c = b & 7;
  const int g = c >> 1;
  const int sub = ((b >> 3) << 1) | (c & 1);
  if (sub >= bpg) return;
  const int n = sub * 256 + (int)threadIdx.x;
  if (n >= npts) return;
  const float px = x[3 * n + 0], py = x[3 * n + 1], pz = x[3 * n + 2];
  const f2* __restrict__ tbl2 = reinterpret_cast<const f2*>(tables);
  f2 accv[3];
#pragma unroll
  for (int k = 0; k < 3; ++k) {
    accv[k] = level_feat(3 * g + k, px, py, pz, tbl2);
  }
  f2* o = reinterpret_cast<f2*>(out + (size_t)n * 24 + g * 6);
  __builtin_nontemporal_store(accv[0], o + 0);
  __builtin_nontemporal_store(accv[1], o + 1);
  __builtin_nontemporal_store(accv[2], o + 2);
}

extern "C" void kernel_launch(void* const* d_in, const int* in_sizes, int n_in,
                              void* d_out, int out_size, void* d_ws, size_t ws_size,
                              hipStream_t stream) {
  const float* x = (const float*)d_in[0];
  const float* tables = (const float*)d_in[1];
  float* out = (float*)d_out;
  const int npts = in_sizes[0] / 3;
  const int nb = (npts + 255) / 256;  // point blocks

  const size_t npad = (size_t)nb * 256;
  // ws layout: hist (128KB, padded to 1MB) | pts 16*npad
  const size_t off_pts = 1u << 20;
  const size_t need = off_pts + 16 * npad;

  if (ws_size >= need) {
    uint8_t* ws = (uint8_t*)d_ws;
    uint32_t* hist = (uint32_t*)ws;
    f4* pts = (f4*)(ws + off_pts);

    hipLaunchKernelGGL(k_zero, dim3((kBuckets + 255) / 256), dim3(256), 0,
                       stream, hist);
    hipLaunchKernelGGL(k_hist, dim3(nb), dim3(256), 0, stream, x, hist, npts);
    hipLaunchKernelGGL(k_scan, dim3(1), dim3(1024), 0, stream, hist);
    hipLaunchKernelGGL(k_scatter, dim3(nb), dim3(256), 0, stream, x, hist, pts,
                       npts);
    hipLaunchKernelGGL(hashenc_part, dim3(8 * nb), dim3(256), 0, stream, pts,
                       tables, out, npts, nb);
  } else {
    const int bpg = nb;
    const int nblocks = 8 * ((bpg + 1) / 2);
    hipLaunchKernelGGL(hashenc_grouped, dim3(nblocks), dim3(256), 0, stream, x,
                       tables, out, npts, bpg);
  }
}

// Round 10
// 569.199 us; speedup vs baseline: 1.1533x; 1.1533x over previous
//
#include <hip/hip_runtime.h>
#include <cstdint>

constexpr int kHashSize = 1 << 17;
constexpr uint32_t kHashMask = (uint32_t)kHashSize - 1u;
constexpr int kBuckets = 32 * 32 * 32;  // spatial sort grid

typedef float f2 __attribute__((ext_vector_type(2)));
typedef float f4 __attribute__((ext_vector_type(4)));

// Static per-level resolutions: max(1, round(16 * b**l)), b = 16^(1/11)
__constant__ float kRes[12] = {16.f,  21.f,  26.f,  34.f,  44.f,  56.f,
                               73.f,  93.f,  120.f, 155.f, 199.f, 256.f};

__device__ __forceinline__ uint32_t cell_of(float px, float py, float pz) {
  uint32_t ix = (uint32_t)min(31, (int)(px * 32.f));
  uint32_t iy = (uint32_t)min(31, (int)(py * 32.f));
  uint32_t iz = (uint32_t)min(31, (int)(pz * 32.f));
  return (ix << 10) | (iy << 5) | iz;
}

// ---------- sort pass 1: histogram, 4 pts/thread, f4 loads ----------
__global__ __launch_bounds__(256) void k_hist(const float* __restrict__ x,
                                              uint32_t* __restrict__ hist,
                                              int npts) {
  int i = blockIdx.x * 256 + threadIdx.x;
  int n0 = i * 4;
  if (n0 + 3 < npts) {
    const f4* xv = reinterpret_cast<const f4*>(x + 3 * n0);
    f4 a = xv[0], b = xv[1], c = xv[2];
    atomicAdd(&hist[cell_of(a.x, a.y, a.z)], 1u);
    atomicAdd(&hist[cell_of(a.w, b.x, b.y)], 1u);
    atomicAdd(&hist[cell_of(b.z, b.w, c.x)], 1u);
    atomicAdd(&hist[cell_of(c.y, c.z, c.w)], 1u);
  } else {
    for (int n = n0; n < npts; ++n)
      atomicAdd(&hist[cell_of(x[3 * n], x[3 * n + 1], x[3 * n + 2])], 1u);
  }
}

// ---------- sort pass 2: exclusive scan, 1 block, uint4 loads ----------
__global__ __launch_bounds__(1024) void k_scan(uint32_t* __restrict__ hist) {
  __shared__ uint32_t lds[1024];
  const int t = threadIdx.x;
  uint4 v[8];
  uint32_t s = 0;
  const uint4* h4 = reinterpret_cast<const uint4*>(hist) + t * 8;
#pragma unroll
  for (int i = 0; i < 8; ++i) {
    v[i] = h4[i];
    s += v[i].x + v[i].y + v[i].z + v[i].w;
  }
  lds[t] = s;
  __syncthreads();
  for (int off = 1; off < 1024; off <<= 1) {
    uint32_t add = (t >= off) ? lds[t - off] : 0u;
    __syncthreads();
    lds[t] += add;
    __syncthreads();
  }
  uint32_t run = lds[t] - s;
  uint4* o4 = reinterpret_cast<uint4*>(hist) + t * 8;
#pragma unroll
  for (int i = 0; i < 8; ++i) {
    uint4 w;
    w.x = run; run += v[i].x;
    w.y = run; run += v[i].y;
    w.z = run; run += v[i].z;
    w.w = run; run += v[i].w;
    o4[i] = w;
  }
}

// ---------- sort pass 3: scatter, 4 pts/thread ----------
__global__ __launch_bounds__(256) void k_scatter(const float* __restrict__ x,
                                                 uint32_t* __restrict__ hist,
                                                 f4* __restrict__ pts, int npts) {
  int i = blockIdx.x * 256 + threadIdx.x;
  int n0 = i * 4;
  if (n0 + 3 < npts) {
    const f4* xv = reinterpret_cast<const f4*>(x + 3 * n0);
    f4 a = xv[0], b = xv[1], c = xv[2];
    float px[4] = {a.x, a.w, b.z, c.y};
    float py[4] = {a.y, b.x, b.w, c.z};
    float pz[4] = {a.z, b.y, c.x, c.w};
#pragma unroll
    for (int k = 0; k < 4; ++k) {
      uint32_t pos = atomicAdd(&hist[cell_of(px[k], py[k], pz[k])], 1u);
      f4 p;
      p.x = px[k]; p.y = py[k]; p.z = pz[k];
      p.w = __uint_as_float((uint32_t)(n0 + k));
      pts[pos] = p;
    }
  } else {
    for (int n = n0; n < npts; ++n) {
      f4 p;
      p.x = x[3 * n + 0]; p.y = x[3 * n + 1]; p.z = x[3 * n + 2];
      p.w = __uint_as_float((uint32_t)n);
      uint32_t pos = atomicAdd(&hist[cell_of(p.x, p.y, p.z)], 1u);
      pts[pos] = p;
    }
  }
}

// ---------- main: XCD-pinned contiguous sorted ranges, all 12 levels ----------
// XCD c (= blockIdx%8) owns sorted point blocks [c*nb8, (c+1)*nb8): uniform
// work per XCD by construction; per-XCD table hot-set ~4.1MB (fine tables
// saturate, mid/coarse collapse to the 1/8-cube restriction).
__global__ __launch_bounds__(256) void hashenc_main(
    const f4* __restrict__ pts,        // [N] sorted {x,y,z,orig}
    const float* __restrict__ tables,  // [12, 131072, 2]
    float* __restrict__ out,           // [N,12,2]
    int npts, int nb8, int nb) {
  const int b = blockIdx.x;
  const int c = b & 7;
  const int r = b >> 3;
  const int pblk = c * nb8 + r;
  if (pblk >= nb) return;
  const int n = pblk * 256 + (int)threadIdx.x;
  if (n >= npts) return;

  const f4 p = pts[n];
  const float px = p.x, py = p.y, pz = p.z;
  const uint32_t orig = __float_as_uint(p.w);

  const f2* __restrict__ tbl2 = reinterpret_cast<const f2*>(tables);

  float acc[12][2];

#pragma unroll
  for (int l = 0; l < 12; ++l) {
    const float rr = kRes[l];
    const float xs = px * rr, ys = py * rr, zs = pz * rr;
    const float fx = floorf(xs), fy = floorf(ys), fz = floorf(zs);
    const float wx = xs - fx, wy = ys - fy, wz = zs - fz;
    const uint32_t ix = (uint32_t)(int32_t)fx;
    const uint32_t iy = (uint32_t)(int32_t)fy;
    const uint32_t iz = (uint32_t)(int32_t)fz;

    // incremental spatial hash (uint32 wraparound == reference int32 semantics)
    const uint32_t hx0 = ix * 73856093u, hx1 = hx0 + 73856093u;
    const uint32_t hy0 = iy * 19349663u, hy1 = hy0 + 19349663u;
    const uint32_t hz0 = iz * 83492791u, hz1 = hz0 + 83492791u;

    const f2* __restrict__ t = tbl2 + (size_t)l * kHashSize;

    const f2 f000 = t[(hx0 ^ hy0 ^ hz0) & kHashMask];
    const f2 f001 = t[(hx0 ^ hy0 ^ hz1) & kHashMask];
    const f2 f010 = t[(hx0 ^ hy1 ^ hz0) & kHashMask];
    const f2 f011 = t[(hx0 ^ hy1 ^ hz1) & kHashMask];
    const f2 f100 = t[(hx1 ^ hy0 ^ hz0) & kHashMask];
    const f2 f101 = t[(hx1 ^ hy0 ^ hz1) & kHashMask];
    const f2 f110 = t[(hx1 ^ hy1 ^ hz0) & kHashMask];
    const f2 f111 = t[(hx1 ^ hy1 ^ hz1) & kHashMask];

    const float ax0 = 1.f - wx, ax1 = wx;
    const float by0 = 1.f - wy, by1 = wy;
    const float cz0 = 1.f - wz, cz1 = wz;
    const float ab00 = ax0 * by0, ab01 = ax0 * by1;
    const float ab10 = ax1 * by0, ab11 = ax1 * by1;
    const float w000 = ab00 * cz0, w001 = ab00 * cz1;
    const float w010 = ab01 * cz0, w011 = ab01 * cz1;
    const float w100 = ab10 * cz0, w101 = ab10 * cz1;
    const float w110 = ab11 * cz0, w111 = ab11 * cz1;

    acc[l][0] = w000 * f000.x + w001 * f001.x + w010 * f010.x + w011 * f011.x +
                w100 * f100.x + w101 * f101.x + w110 * f110.x + w111 * f111.x;
    acc[l][1] = w000 * f000.y + w001 * f001.y + w010 * f010.y + w011 * f011.y +
                w100 * f100.y + w101 * f101.y + w110 * f110.y + w111 * f111.y;
  }

  // full 96B record to out[orig]: 6 nontemporal float4 stores (16B aligned)
  f4* o = reinterpret_cast<f4*>(out + (size_t)orig * 24);
#pragma unroll
  for (int k = 0; k < 6; ++k) {
    f4 v;
    v.x = acc[2 * k + 0][0];
    v.y = acc[2 * k + 0][1];
    v.z = acc[2 * k + 1][0];
    v.w = acc[2 * k + 1][1];
    __builtin_nontemporal_store(v, o + k);
  }
}

// ---------- fallback (round-5 kernel, 410us) if ws too small ----------
__global__ __launch_bounds__(256) void hashenc_grouped(
    const float* __restrict__ x, const float* __restrict__ tables,
    float* __restrict__ out, int npts, int bpg) {
  const int b = blockIdx.x;
  const int c = b & 7;
  const int g = c >> 1;
  const int sub = ((b >> 3) << 1) | (c & 1);
  if (sub >= bpg) return;
  const int n = sub * 256 + (int)threadIdx.x;
  if (n >= npts) return;
  const float px = x[3 * n + 0], py = x[3 * n + 1], pz = x[3 * n + 2];
  const f2* __restrict__ tbl2 = reinterpret_cast<const f2*>(tables);
  f2 accv[3];
#pragma unroll
  for (int k = 0; k < 3; ++k) {
    const int l = 3 * g + k;
    const float rr = kRes[l];
    const float xs = px * rr, ys = py * rr, zs = pz * rr;
    const float fx = floorf(xs), fy = floorf(ys), fz = floorf(zs);
    const float wx = xs - fx, wy = ys - fy, wz = zs - fz;
    const uint32_t ix = (uint32_t)(int32_t)fx;
    const uint32_t iy = (uint32_t)(int32_t)fy;
    const uint32_t iz = (uint32_t)(int32_t)fz;
    const uint32_t hx0 = ix * 73856093u, hx1 = hx0 + 73856093u;
    const uint32_t hy0 = iy * 19349663u, hy1 = hy0 + 19349663u;
    const uint32_t hz0 = iz * 83492791u, hz1 = hz0 + 83492791u;
    const f2* __restrict__ t = tbl2 + (size_t)l * kHashSize;
    const f2 f000 = t[(hx0 ^ hy0 ^ hz0) & kHashMask];
    const f2 f001 = t[(hx0 ^ hy0 ^ hz1) & kHashMask];
    const f2 f010 = t[(hx0 ^ hy1 ^ hz0) & kHashMask];
    const f2 f011 = t[(hx0 ^ hy1 ^ hz1) & kHashMask];
    const f2 f100 = t[(hx1 ^ hy0 ^ hz0) & kHashMask];
    const f2 f101 = t[(hx1 ^ hy0 ^ hz1) & kHashMask];
    const f2 f110 = t[(hx1 ^ hy1 ^ hz0) & kHashMask];
    const f2 f111 = t[(hx1 ^ hy1 ^ hz1) & kHashMask];
    const float ax0 = 1.f - wx, ax1 = wx;
    const float by0 = 1.f - wy, by1 = wy;
    const float cz0 = 1.f - wz, cz1 = wz;
    const float ab00 = ax0 * by0, ab01 = ax0 * by1;
    const float ab10 = ax1 * by0, ab11 = ax1 * by1;
    const float w000 = ab00 * cz0, w001 = ab00 * cz1;
    const float w010 = ab01 * cz0, w011 = ab01 * cz1;
    const float w100 = ab10 * cz0, w101 = ab10 * cz1;
    const float w110 = ab11 * cz0, w111 = ab11 * cz1;
    f2 a;
    a.x = w000 * f000.x + w001 * f001.x + w010 * f010.x + w011 * f011.x +
          w100 * f100.x + w101 * f101.x + w110 * f110.x + w111 * f111.x;
    a.y = w000 * f000.y + w001 * f001.y + w010 * f010.y + w011 * f011.y +
          w100 * f100.y + w101 * f101.y + w110 * f110.y + w111 * f111.y;
    accv[k] = a;
  }
  f2* o = reinterpret_cast<f2*>(out + (size_t)n * 24 + g * 6);
  __builtin_nontemporal_store(accv[0], o + 0);
  __builtin_nontemporal_store(accv[1], o + 1);
  __builtin_nontemporal_store(accv[2], o + 2);
}

extern "C" void kernel_launch(void* const* d_in, const int* in_sizes, int n_in,
                              void* d_out, int out_size, void* d_ws, size_t ws_size,
                              hipStream_t stream) {
  const float* x = (const float*)d_in[0];
  const float* tables = (const float*)d_in[1];
  float* out = (float*)d_out;
  const int npts = in_sizes[0] / 3;
  const int nb = (npts + 255) / 256;  // point blocks
  const int nb8 = (nb + 7) / 8;       // point blocks per XCD

  const size_t npad = (size_t)nb * 256;
  // ws layout: hist (128KB, padded to 1MB) | pts 16*npad
  const size_t off_pts = 1u << 20;
  const size_t need = off_pts + 16 * npad;

  if (ws_size >= need) {
    uint8_t* ws = (uint8_t*)d_ws;
    uint32_t* hist = (uint32_t*)ws;
    f4* pts = (f4*)(ws + off_pts);

    hipMemsetAsync(hist, 0, kBuckets * sizeof(uint32_t), stream);
    const int nq = ((npts + 3) / 4 + 255) / 256;  // 4 pts/thread grids
    hipLaunchKernelGGL(k_hist, dim3(nq), dim3(256), 0, stream, x, hist, npts);
    hipLaunchKernelGGL(k_scan, dim3(1), dim3(1024), 0, stream, hist);
    hipLaunchKernelGGL(k_scatter, dim3(nq), dim3(256), 0, stream, x, hist, pts,
                       npts);
    hipLaunchKernelGGL(hashenc_main, dim3(8 * nb8), dim3(256), 0, stream, pts,
                       tables, out, npts, nb8, nb);
  } else {
    const int bpg = nb;
    const int nblocks = 8 * ((bpg + 1) / 2);
    hipLaunchKernelGGL(hashenc_grouped, dim3(nblocks), dim3(256), 0, stream, x,
                       tables, out, npts, bpg);
  }
}

// Round 11
// 458.268 us; speedup vs baseline: 1.4325x; 1.2421x over previous
//
#include <hip/hip_runtime.h>
#include <cstdint>

constexpr int kHashSize = 1 << 17;
constexpr uint32_t kHashMask = (uint32_t)kHashSize - 1u;

typedef float f2 __attribute__((ext_vector_type(2)));
typedef float f4 __attribute__((ext_vector_type(4)));

// Static per-level resolutions: max(1, round(16 * b**l)), b = 16^(1/11)
__constant__ float kRes[12] = {16.f,  21.f,  26.f,  34.f,  44.f,  56.f,
                               73.f,  93.f,  120.f, 155.f, 199.f, 256.f};

// Dense LUT dims for coarse levels (corners 0..R inclusive)
constexpr int kD0 = 17;  // level 0, R=16
constexpr int kD1 = 22;  // level 1, R=21
constexpr int kN0 = kD0 * kD0 * kD0;  // 4913
constexpr int kN1 = kD1 * kD1 * kD1;  // 10648
// LDS LUT: (4913+10648)*8B = 124,488 B  (gfx950 supports >=128KB static LDS)

// ---------- hashed-table trilinear feature ----------
__device__ __forceinline__ f2 level_feat(int l, float px, float py, float pz,
                                         const f2* __restrict__ tbl2) {
  const float r = kRes[l];
  const float xs = px * r, ys = py * r, zs = pz * r;
  const float fx = floorf(xs), fy = floorf(ys), fz = floorf(zs);
  const float wx = xs - fx, wy = ys - fy, wz = zs - fz;
  const uint32_t ix = (uint32_t)(int32_t)fx;
  const uint32_t iy = (uint32_t)(int32_t)fy;
  const uint32_t iz = (uint32_t)(int32_t)fz;
  // incremental spatial hash (uint32 wraparound == reference int32 semantics)
  const uint32_t hx0 = ix * 73856093u, hx1 = hx0 + 73856093u;
  const uint32_t hy0 = iy * 19349663u, hy1 = hy0 + 19349663u;
  const uint32_t hz0 = iz * 83492791u, hz1 = hz0 + 83492791u;
  const f2* __restrict__ t = tbl2 + (size_t)l * kHashSize;
  const f2 f000 = t[(hx0 ^ hy0 ^ hz0) & kHashMask];
  const f2 f001 = t[(hx0 ^ hy0 ^ hz1) & kHashMask];
  const f2 f010 = t[(hx0 ^ hy1 ^ hz0) & kHashMask];
  const f2 f011 = t[(hx0 ^ hy1 ^ hz1) & kHashMask];
  const f2 f100 = t[(hx1 ^ hy0 ^ hz0) & kHashMask];
  const f2 f101 = t[(hx1 ^ hy0 ^ hz1) & kHashMask];
  const f2 f110 = t[(hx1 ^ hy1 ^ hz0) & kHashMask];
  const f2 f111 = t[(hx1 ^ hy1 ^ hz1) & kHashMask];
  const float ax0 = 1.f - wx, ax1 = wx;
  const float by0 = 1.f - wy, by1 = wy;
  const float cz0 = 1.f - wz, cz1 = wz;
  const float ab00 = ax0 * by0, ab01 = ax0 * by1;
  const float ab10 = ax1 * by0, ab11 = ax1 * by1;
  const float w000 = ab00 * cz0, w001 = ab00 * cz1;
  const float w010 = ab01 * cz0, w011 = ab01 * cz1;
  const float w100 = ab10 * cz0, w101 = ab10 * cz1;
  const float w110 = ab11 * cz0, w111 = ab11 * cz1;
  f2 a;
  a.x = w000 * f000.x + w001 * f001.x + w010 * f010.x + w011 * f011.x +
        w100 * f100.x + w101 * f101.x + w110 * f110.x + w111 * f111.x;
  a.y = w000 * f000.y + w001 * f001.y + w010 * f010.y + w011 * f011.y +
        w100 * f100.y + w101 * f101.y + w110 * f110.y + w111 * f111.y;
  return a;
}

// ---------- dense-LDS trilinear feature ----------
__device__ __forceinline__ f2 lut_feat(const f2* lut, int D, float res,
                                       float px, float py, float pz) {
  const float xs = px * res, ys = py * res, zs = pz * res;
  const float fx = floorf(xs), fy = floorf(ys), fz = floorf(zs);
  const float wx = xs - fx, wy = ys - fy, wz = zs - fz;
  const int ix = (int)fx, iy = (int)fy, iz = (int)fz;
  const int i000 = (ix * D + iy) * D + iz;
  const f2 f000 = lut[i000],            f001 = lut[i000 + 1];
  const f2 f010 = lut[i000 + D],        f011 = lut[i000 + D + 1];
  const f2 f100 = lut[i000 + D * D],    f101 = lut[i000 + D * D + 1];
  const f2 f110 = lut[i000 + D * D + D], f111 = lut[i000 + D * D + D + 1];
  const float ax0 = 1.f - wx, ax1 = wx;
  const float by0 = 1.f - wy, by1 = wy;
  const float cz0 = 1.f - wz, cz1 = wz;
  const float ab00 = ax0 * by0, ab01 = ax0 * by1;
  const float ab10 = ax1 * by0, ab11 = ax1 * by1;
  const float w000 = ab00 * cz0, w001 = ab00 * cz1;
  const float w010 = ab01 * cz0, w011 = ab01 * cz1;
  const float w100 = ab10 * cz0, w101 = ab10 * cz1;
  const float w110 = ab11 * cz0, w111 = ab11 * cz1;
  f2 a;
  a.x = w000 * f000.x + w001 * f001.x + w010 * f010.x + w011 * f011.x +
        w100 * f100.x + w101 * f101.x + w110 * f110.x + w111 * f111.x;
  a.y = w000 * f000.y + w001 * f001.y + w010 * f010.y + w011 * f011.y +
        w100 * f100.y + w101 * f101.y + w110 * f110.y + w111 * f111.y;
  return a;
}

// ---------- kernel A: levels 0-3 (L0/L1 from dense LDS LUT, L2/L3 gathered) --
// 256 blocks x 1024 threads, 124KB LDS -> 1 block/CU, 16 waves/CU.
// Writes record floats [0,8) as 2x f4 nt.
__global__ __launch_bounds__(1024) void henc_A(const float* __restrict__ x,
                                               const float* __restrict__ tables,
                                               float* __restrict__ out,
                                               int npts, int ppb) {
  __shared__ f2 lut[kN0 + kN1];
  const int t = threadIdx.x;
  const f2* __restrict__ tbl2 = reinterpret_cast<const f2*>(tables);

  // stage dense L0 LUT: lut[(ix*17+iy)*17+iz] = table0[hash & mask]
  for (int i = t; i < kN0; i += 1024) {
    int iz = i % kD0;
    int rr = i / kD0;
    int iy = rr % kD0;
    int ix = rr / kD0;
    uint32_t h = (uint32_t)ix * 73856093u ^ (uint32_t)iy * 19349663u ^
                 (uint32_t)iz * 83492791u;
    lut[i] = tbl2[h & kHashMask];
  }
  // stage dense L1 LUT at offset kN0
  for (int i = t; i < kN1; i += 1024) {
    int iz = i % kD1;
    int rr = i / kD1;
    int iy = rr % kD1;
    int ix = rr / kD1;
    uint32_t h = (uint32_t)ix * 73856093u ^ (uint32_t)iy * 19349663u ^
                 (uint32_t)iz * 83492791u;
    lut[kN0 + i] = tbl2[(size_t)kHashSize + (h & kHashMask)];
  }
  __syncthreads();

  const int base = blockIdx.x * ppb;
  for (int i = t; i < ppb; i += 1024) {
    const int n = base + i;
    if (n >= npts) continue;
    const float px = __builtin_nontemporal_load(x + 3 * n + 0);
    const float py = __builtin_nontemporal_load(x + 3 * n + 1);
    const float pz = __builtin_nontemporal_load(x + 3 * n + 2);

    const f2 a0 = lut_feat(lut, kD0, 16.f, px, py, pz);
    const f2 a1 = lut_feat(lut + kN0, kD1, 21.f, px, py, pz);
    const f2 a2 = level_feat(2, px, py, pz, tbl2);
    const f2 a3 = level_feat(3, px, py, pz, tbl2);

    f4 v0, v1;
    v0.x = a0.x; v0.y = a0.y; v0.z = a1.x; v0.w = a1.y;
    v1.x = a2.x; v1.y = a2.y; v1.z = a3.x; v1.w = a3.y;
    f4* o = reinterpret_cast<f4*>(out + (size_t)n * 24);
    __builtin_nontemporal_store(v0, o + 0);
    __builtin_nontemporal_store(v1, o + 1);
  }
}

// ---------- kernel B: levels 4-11, XCD-pinned (chunk, point-half) ----------
// XCD c (= blockIdx%8, round-robin verified R5): chunk = c>>1 in
// {L4L5,L6L7,L8L9,L10L11}, half = c&1 of points. 8M req/XCD balanced by
// construction; 2MB tables per XCD -> L2 resident. Writes one f4 chunk at
// record float 8 + chunk*4.
__global__ __launch_bounds__(256) void henc_B(const float* __restrict__ x,
                                              const float* __restrict__ tables,
                                              float* __restrict__ out,
                                              int npts, int nb2) {
  const int b = blockIdx.x;
  const int c = b & 7;
  const int r = b >> 3;
  const int chunk = c >> 1;
  const int half = c & 1;
  const int pblk = half * nb2 + r;
  const int n = pblk * 256 + (int)threadIdx.x;
  if (n >= npts) return;

  const float px = __builtin_nontemporal_load(x + 3 * n + 0);
  const float py = __builtin_nontemporal_load(x + 3 * n + 1);
  const float pz = __builtin_nontemporal_load(x + 3 * n + 2);

  const f2* __restrict__ tbl2 = reinterpret_cast<const f2*>(tables);
  const int l0 = 4 + 2 * chunk;
  const f2 a = level_feat(l0, px, py, pz, tbl2);
  const f2 b2 = level_feat(l0 + 1, px, py, pz, tbl2);

  f4 v;
  v.x = a.x; v.y = a.y; v.z = b2.x; v.w = b2.y;
  __builtin_nontemporal_store(
      v, reinterpret_cast<f4*>(out + (size_t)n * 24 + 8 + 4 * chunk));
}

extern "C" void kernel_launch(void* const* d_in, const int* in_sizes, int n_in,
                              void* d_out, int out_size, void* d_ws, size_t ws_size,
                              hipStream_t stream) {
  const float* x = (const float*)d_in[0];
  const float* tables = (const float*)d_in[1];
  float* out = (float*)d_out;
  const int npts = in_sizes[0] / 3;
  const int nb = (npts + 255) / 256;   // 256-pt blocks
  const int nb2 = (nb + 1) / 2;        // point-half blocks for kernel B
  const int ppb = (npts + 255) / 256;  // points per A-block (256 blocks)

  hipLaunchKernelGGL(henc_A, dim3(256), dim3(1024), 0, stream, x, tables, out,
                     npts, ppb);
  hipLaunchKernelGGL(henc_B, dim3(8 * nb2), dim3(256), 0, stream, x, tables,
                     out, npts, nb2);
}